// Round 11
// baseline (816.215 us; speedup 1.0000x reference)
//
#include <hip/hip_runtime.h>
#include <hip/hip_fp16.h>

#define FDIM 64
#define NB_SHIFT 10                  // 1024 nodes per bucket
#define NB_PAD 256                   // padded scan width (NB <= 256)
#define CH 4096                      // edges per bin-chunk

typedef __attribute__((ext_vector_type(8))) _Float16 half8;
typedef __attribute__((ext_vector_type(4))) float floatx4;

// ---------------- bucket-level CSR build (no per-node global atomics) ----------------

// 196-bucket histogram: LDS-local, one global atomicAdd per bucket per block.
__global__ __launch_bounds__(256) void bucket_hist_kernel(
        const int* __restrict__ dst, int* __restrict__ bucket_cnt, int E) {
    __shared__ int h[NB_PAD];
    for (int i = threadIdx.x; i < NB_PAD; i += 256) h[i] = 0;
    __syncthreads();
    int stride = gridDim.x * 256;
    for (int e = blockIdx.x * 256 + threadIdx.x; e < E; e += stride)
        atomicAdd(&h[dst[e] >> NB_SHIFT], 1);
    __syncthreads();
    for (int i = threadIdx.x; i < NB_PAD; i += 256)
        if (h[i]) atomicAdd(&bucket_cnt[i], h[i]);
}

// single block: exclusive scan of bucket counts -> bucket_base[0..NB] and cursors.
__global__ __launch_bounds__(256) void bucket_scan_kernel(
        const int* __restrict__ bucket_cnt, int* __restrict__ bucket_base,
        int* __restrict__ bucket_cursor) {
    __shared__ int s[NB_PAD];
    int t = threadIdx.x;
    int v = bucket_cnt[t];
    s[t] = v;
    __syncthreads();
    for (int off = 1; off < 256; off <<= 1) {
        int x = (t >= off) ? s[t - off] : 0;
        __syncthreads();
        s[t] += x;
        __syncthreads();
    }
    int excl = s[t] - v;
    bucket_base[t] = excl;                  // for t >= NB this equals E (cnt=0)
    if (t == 255) bucket_base[256] = s[255];
    bucket_cursor[t] = excl;
}

// Stage 1: bin edges by dst bucket with LDS staging + chunked coalesced flush.
__global__ __launch_bounds__(256) void bin_kernel(
        const int* __restrict__ src, const int* __restrict__ dst,
        const float* __restrict__ w, int* __restrict__ bucket_cursor,
        int2* __restrict__ binned_sv, unsigned short* __restrict__ binned_d,
        int E, int NB) {
    __shared__ int2 stage_sv[CH];           // 32 KB
    __shared__ int  stage_d[CH];            // 16 KB
    __shared__ int hist[NB_PAD], offs0[NB_PAD], run[NB_PAD], base[NB_PAD];

    int t = threadIdx.x;
    int c0 = blockIdx.x * CH;
    int valid = E - c0; if (valid > CH) valid = CH;

    for (int b = t; b < NB_PAD; b += 256) hist[b] = 0;
    __syncthreads();

    int  myd[16];
    int2 mysv[16];
    #pragma unroll
    for (int j = 0; j < 16; ++j) {
        int i = t + j * 256;
        if (i < valid) {
            int e = c0 + i;
            int d = dst[e];
            myd[j] = d;
            mysv[j] = make_int2(src[e], __float_as_int(-w[e]));  // norm = -w
            atomicAdd(&hist[d >> NB_SHIFT], 1);
        } else myd[j] = -1;
    }
    __syncthreads();

    // inclusive scan of hist (256-wide Hillis-Steele) -> exclusive offs
    offs0[t] = hist[t];
    __syncthreads();
    for (int off = 1; off < 256; off <<= 1) {
        int x = (t >= off) ? offs0[t - off] : 0;
        __syncthreads();
        offs0[t] += x;
        __syncthreads();
    }
    int cnt_b = hist[t];
    int excl = offs0[t] - cnt_b;
    __syncthreads();
    offs0[t] = excl;
    run[t] = excl;
    base[t] = (t < NB && cnt_b > 0) ? atomicAdd(&bucket_cursor[t], cnt_b) : 0;
    __syncthreads();

    // scatter into LDS grouped by bucket
    #pragma unroll
    for (int j = 0; j < 16; ++j) {
        if (myd[j] >= 0) {
            int b = myd[j] >> NB_SHIFT;
            int pos = atomicAdd(&run[b], 1);
            stage_sv[pos] = mysv[j];
            stage_d[pos]  = myd[j];
        }
    }
    __syncthreads();

    // flush: consecutive LDS entries of a bucket -> consecutive global slots
    for (int i = t; i < valid; i += 256) {
        int d = stage_d[i];
        int b = d >> NB_SHIFT;
        int g = base[b] + (i - offs0[b]);
        binned_sv[g] = stage_sv[i];
        binned_d[g]  = (unsigned short)(d & ((1 << NB_SHIFT) - 1));
    }
}

// Stage 2: one 1024-thread block per bucket. Local histogram + local scan in LDS
// produce row_start/counts for the bucket's nodes (no global atomics), then edges
// are placed; the ~130KB CSR window stays in ONE XCD's L2.
__global__ __launch_bounds__(1024) void csr_kernel(
        const int* __restrict__ bucket_base, const int2* __restrict__ binned_sv,
        const unsigned short* __restrict__ binned_d,
        int* __restrict__ row_start, int* __restrict__ counts,
        int2* __restrict__ colval, int N) {
    __shared__ int lhist[1 << NB_SHIFT];    // 4 KB
    __shared__ int lscan[1 << NB_SHIFT];    // 4 KB
    int b = blockIdx.x;
    int t = threadIdx.x;
    int nbase = b << NB_SHIFT;
    int lo = bucket_base[b];
    int hi = bucket_base[b + 1];

    lhist[t] = 0;
    __syncthreads();
    for (int i = lo + t; i < hi; i += 1024)
        atomicAdd(&lhist[binned_d[i]], 1);
    __syncthreads();

    int v = lhist[t];
    lscan[t] = v;
    __syncthreads();
    for (int off = 1; off < 1024; off <<= 1) {
        int x = (t >= off) ? lscan[t - off] : 0;
        __syncthreads();
        lscan[t] += x;
        __syncthreads();
    }
    int rs = lo + lscan[t] - v;             // node's CSR start
    int node = nbase + t;
    if (node < N) {
        row_start[node] = rs;
        counts[node] = v;
    }
    __syncthreads();
    lscan[t] = rs;                          // reuse as local cursor
    __syncthreads();

    for (int i = lo + t; i < hi; i += 1024) {
        int2 sv = binned_sv[i];
        int p = atomicAdd(&lscan[binned_d[i]], 1);
        colval[p] = sv;
    }
}

// ---------------- convert x -> fp16 (T0') ----------------

__global__ void convert_kernel(const float* __restrict__ x, __half* __restrict__ XH,
                               int total) {
    int i = (blockIdx.x * blockDim.x + threadIdx.x) * 4;
    if (i < total) {
        float4 v = *(const float4*)(x + i);
        __half2 h0 = __floats2half2_rn(v.x, v.y);
        __half2 h1 = __floats2half2_rn(v.z, v.w);
        int2 packed = make_int2(*(int*)&h0, *(int*)&h1);
        *(int2*)((char*)XH + (size_t)i * 2) = packed;
    }
}

// ---------------- prep W'T: WT[o][tk*64+fin] = 4^tk * W[tk][fin][o], fp16 ----------------

__global__ void prep_wt_kernel(const float* __restrict__ W, __half* __restrict__ WT,
                               int K) {
    int i = blockIdx.x * blockDim.x + threadIdx.x;     // over K*64*64
    if (i < K * FDIM * FDIM) {
        int tk  = i / (FDIM * FDIM);
        int rem = i - tk * FDIM * FDIM;
        int fin = rem >> 6;
        int o   = rem & 63;
        float sig = (float)(1 << (2 * tk));            // 4^tk
        WT[(size_t)o * (K * FDIM) + tk * FDIM + fin] = __float2half(sig * W[i]);
    }
}

// ---------------- Chebyshev passes ----------------
// Wave per node, lane = feature. Stored T's are fp16, scaled by sigma_k = 4^k.
// Edge list (<=64 edges) loaded with ONE per-lane NONTEMPORAL int2 load (edge
// stream is read once -- keep it out of L2 so gather rows stay cached),
// broadcast via __shfl. 16/8/4-deep gather batching for outstanding-miss depth.

#define GATHER_LOOP(SRC, ACC)                                                       \
    {                                                                               \
        int m = (cnt < 64) ? cnt : 64;                                              \
        long long q = (lane < m)                                                    \
            ? __builtin_nontemporal_load((const long long*)cv + lane) : 0ll;        \
        int cx = (int)(unsigned int)(q & 0xffffffffll);                             \
        float vv = __int_as_float((int)(q >> 32));                                  \
        int j = 0;                                                                  \
        for (; j + 16 <= m; j += 16) {                                              \
            int c0 = __shfl(cx, j+0);  float v0 = __shfl(vv, j+0);                  \
            int c1 = __shfl(cx, j+1);  float v1 = __shfl(vv, j+1);                  \
            int c2 = __shfl(cx, j+2);  float v2 = __shfl(vv, j+2);                  \
            int c3 = __shfl(cx, j+3);  float v3 = __shfl(vv, j+3);                  \
            int c4 = __shfl(cx, j+4);  float v4 = __shfl(vv, j+4);                  \
            int c5 = __shfl(cx, j+5);  float v5 = __shfl(vv, j+5);                  \
            int c6 = __shfl(cx, j+6);  float v6 = __shfl(vv, j+6);                  \
            int c7 = __shfl(cx, j+7);  float v7 = __shfl(vv, j+7);                  \
            int c8 = __shfl(cx, j+8);  float v8 = __shfl(vv, j+8);                  \
            int c9 = __shfl(cx, j+9);  float v9 = __shfl(vv, j+9);                  \
            int ca = __shfl(cx, j+10); float va = __shfl(vv, j+10);                 \
            int cb = __shfl(cx, j+11); float vb = __shfl(vv, j+11);                 \
            int cc = __shfl(cx, j+12); float vc = __shfl(vv, j+12);                 \
            int cd = __shfl(cx, j+13); float vd = __shfl(vv, j+13);                 \
            int ce = __shfl(cx, j+14); float ve = __shfl(vv, j+14);                 \
            int cf = __shfl(cx, j+15); float vf = __shfl(vv, j+15);                 \
            float t0 = __half2float(SRC[(size_t)c0 * FDIM + lane]);                 \
            float t1 = __half2float(SRC[(size_t)c1 * FDIM + lane]);                 \
            float t2 = __half2float(SRC[(size_t)c2 * FDIM + lane]);                 \
            float t3 = __half2float(SRC[(size_t)c3 * FDIM + lane]);                 \
            float t4 = __half2float(SRC[(size_t)c4 * FDIM + lane]);                 \
            float t5 = __half2float(SRC[(size_t)c5 * FDIM + lane]);                 \
            float t6 = __half2float(SRC[(size_t)c6 * FDIM + lane]);                 \
            float t7 = __half2float(SRC[(size_t)c7 * FDIM + lane]);                 \
            float t8 = __half2float(SRC[(size_t)c8 * FDIM + lane]);                 \
            float t9 = __half2float(SRC[(size_t)c9 * FDIM + lane]);                 \
            float ta = __half2float(SRC[(size_t)ca * FDIM + lane]);                 \
            float tb = __half2float(SRC[(size_t)cb * FDIM + lane]);                 \
            float tc = __half2float(SRC[(size_t)cc * FDIM + lane]);                 \
            float td = __half2float(SRC[(size_t)cd * FDIM + lane]);                 \
            float te = __half2float(SRC[(size_t)ce * FDIM + lane]);                 \
            float tf = __half2float(SRC[(size_t)cf * FDIM + lane]);                 \
            ACC += v0*t0 + v1*t1 + v2*t2 + v3*t3 + v4*t4 + v5*t5 + v6*t6 + v7*t7;   \
            ACC += v8*t8 + v9*t9 + va*ta + vb*tb + vc*tc + vd*td + ve*te + vf*tf;   \
        }                                                                           \
        for (; j + 8 <= m; j += 8) {                                                \
            int c0 = __shfl(cx, j+0); float v0 = __shfl(vv, j+0);                   \
            int c1 = __shfl(cx, j+1); float v1 = __shfl(vv, j+1);                   \
            int c2 = __shfl(cx, j+2); float v2 = __shfl(vv, j+2);                   \
            int c3 = __shfl(cx, j+3); float v3 = __shfl(vv, j+3);                   \
            int c4 = __shfl(cx, j+4); float v4 = __shfl(vv, j+4);                   \
            int c5 = __shfl(cx, j+5); float v5 = __shfl(vv, j+5);                   \
            int c6 = __shfl(cx, j+6); float v6 = __shfl(vv, j+6);                   \
            int c7 = __shfl(cx, j+7); float v7 = __shfl(vv, j+7);                   \
            float t0 = __half2float(SRC[(size_t)c0 * FDIM + lane]);                 \
            float t1 = __half2float(SRC[(size_t)c1 * FDIM + lane]);                 \
            float t2 = __half2float(SRC[(size_t)c2 * FDIM + lane]);                 \
            float t3 = __half2float(SRC[(size_t)c3 * FDIM + lane]);                 \
            float t4 = __half2float(SRC[(size_t)c4 * FDIM + lane]);                 \
            float t5 = __half2float(SRC[(size_t)c5 * FDIM + lane]);                 \
            float t6 = __half2float(SRC[(size_t)c6 * FDIM + lane]);                 \
            float t7 = __half2float(SRC[(size_t)c7 * FDIM + lane]);                 \
            ACC += v0*t0 + v1*t1 + v2*t2 + v3*t3 + v4*t4 + v5*t5 + v6*t6 + v7*t7;   \
        }                                                                           \
        for (; j + 4 <= m; j += 4) {                                                \
            int c0 = __shfl(cx, j+0); float v0 = __shfl(vv, j+0);                   \
            int c1 = __shfl(cx, j+1); float v1 = __shfl(vv, j+1);                   \
            int c2 = __shfl(cx, j+2); float v2 = __shfl(vv, j+2);                   \
            int c3 = __shfl(cx, j+3); float v3 = __shfl(vv, j+3);                   \
            float t0 = __half2float(SRC[(size_t)c0 * FDIM + lane]);                 \
            float t1 = __half2float(SRC[(size_t)c1 * FDIM + lane]);                 \
            float t2 = __half2float(SRC[(size_t)c2 * FDIM + lane]);                 \
            float t3 = __half2float(SRC[(size_t)c3 * FDIM + lane]);                 \
            ACC += v0*t0 + v1*t1 + v2*t2 + v3*t3;                                   \
        }                                                                           \
        for (; j < m; ++j) {                                                        \
            int c = __shfl(cx, j); float v = __shfl(vv, j);                         \
            ACC += v * __half2float(SRC[(size_t)c * FDIM + lane]);                  \
        }                                                                           \
        for (int e2 = 64; e2 < cnt; ++e2) {  /* astronomically rare */              \
            int2 a = cv[e2];                                                        \
            ACC += __int_as_float(a.y) * __half2float(SRC[(size_t)a.x * FDIM + lane]); \
        }                                                                           \
    }

__global__ __launch_bounds__(256, 8) void pass1_kernel(
        const __half* __restrict__ XH, const int* __restrict__ row_start,
        const int* __restrict__ counts, const int2* __restrict__ colval,
        __half* __restrict__ T1H, int N) {
    int wid = threadIdx.x >> 6;
    int lane = threadIdx.x & 63;
    int node = blockIdx.x * 4 + wid;
    if (node >= N) return;

    float acc = -__half2float(XH[(size_t)node * FDIM + lane]);   // self loop (norm -1)
    int s = row_start[node];
    int cnt = counts[node];
    const int2* cv = colval + s;
    GATHER_LOOP(XH, acc)
    // T1 store: nontemporal (written once, read by next pass much later)
    unsigned short bits = __half_as_ushort(__float2half(acc * 0.25f));   // sigma1=4
    __builtin_nontemporal_store(bits, (unsigned short*)(T1H + (size_t)node * FDIM + lane));
}

// T'_next = 0.5*prop'(T'_cur) - T'_prev/16
__global__ __launch_bounds__(256, 8) void passk_kernel(
        const __half* __restrict__ TcH, const __half* __restrict__ TpH,
        __half* __restrict__ TnH, const int* __restrict__ row_start,
        const int* __restrict__ counts, const int2* __restrict__ colval, int N) {
    int wid = threadIdx.x >> 6;
    int lane = threadIdx.x & 63;
    int node = blockIdx.x * 4 + wid;
    if (node >= N) return;

    size_t self = (size_t)node * FDIM + lane;
    int s = row_start[node];
    int cnt = counts[node];
    const int2* cv = colval + s;
    float acc = -__half2float(TcH[self]);                        // self loop (cached plane)
    GATHER_LOOP(TcH, acc)
    // Tp self read + Tn store: nontemporal (pure streams, keep out of L2)
    unsigned short tpbits = __builtin_nontemporal_load((const unsigned short*)(TpH + self));
    float tp = __half2float(__ushort_as_half(tpbits));
    float tns = 0.5f * acc - 0.0625f * tp;
    unsigned short bits = __half_as_ushort(__float2half(tns));
    __builtin_nontemporal_store(bits, (unsigned short*)(TnH + self));
}

// ---------------- final: out = [T'0|...|T'5] @ W'T^T + bias via MFMA ----------------

__global__ __launch_bounds__(256) void final_mfma_kernel(
        const __half* __restrict__ Tall, const __half* __restrict__ WT,
        const float* __restrict__ bias, float* __restrict__ out,
        int N, int K) {
    int wid = threadIdx.x >> 6;
    int lane = threadIdx.x & 63;
    int tile = blockIdx.x * 4 + wid;       // 16 nodes per wave-tile
    int nodeBase = tile << 4;
    if (nodeBase >= N) return;
    size_t NT = (size_t)N * FDIM;
    int Kflat = K * FDIM;                  // 384

    int m = lane & 15;
    int kgrp = lane >> 4;                  // 0..3
    int nodeA = nodeBase + m;              // A-fragment row
    bool aok = nodeA < N;

    floatx4 acc[4];
    #pragma unroll
    for (int f = 0; f < 4; ++f) {
        float bv = bias[f * 16 + m];
        acc[f] = (floatx4){bv, bv, bv, bv};
    }

    for (int kc = 0; kc < Kflat / 32; ++kc) {
        int tk = kc >> 1;
        int feat = ((kc & 1) << 5) + (kgrp << 3);    // 0..56, 8-aligned
        half8 a = aok ? *(const half8*)(Tall + (size_t)tk * NT + (size_t)nodeA * FDIM + feat)
                      : (half8)(_Float16)0;
        int kOff = (kc << 5) + (kgrp << 3);
        #pragma unroll
        for (int f = 0; f < 4; ++f) {
            half8 b = *(const half8*)(WT + (size_t)(f * 16 + m) * Kflat + kOff);
            acc[f] = __builtin_amdgcn_mfma_f32_16x16x32_f16(a, b, acc[f], 0, 0, 0);
        }
    }

    #pragma unroll
    for (int f = 0; f < 4; ++f) {
        #pragma unroll
        for (int r = 0; r < 4; ++r) {
            int nrow = nodeBase + (kgrp << 2) + r;
            if (nrow < N) out[(size_t)nrow * FDIM + f * 16 + m] = acc[f][r];
        }
    }
}

// ---------------- host ----------------

extern "C" void kernel_launch(void* const* d_in, const int* in_sizes, int n_in,
                              void* d_out, int out_size, void* d_ws, size_t ws_size,
                              hipStream_t stream) {
    const float* x      = (const float*)d_in[0];
    const int*   idx    = (const int*)d_in[1];
    const float* w      = (const float*)d_in[2];
    const float* weight = (const float*)d_in[3];
    const float* bias   = (const float*)d_in[4];
    float* out = (float*)d_out;

    const int N = in_sizes[0] / FDIM;
    const int E = in_sizes[2];
    const int K = in_sizes[3] / (FDIM * FDIM);
    const int NB = (N + (1 << NB_SHIFT) - 1) >> NB_SHIFT;

    const int* src = idx;
    const int* dst = idx + E;

    int* counts        = (int*)d_ws;                 // N
    int* row_start     = counts + N;                 // N
    int* bucket_cnt    = row_start + N;              // 256
    int* bucket_base   = bucket_cnt + 256;           // 260
    int* bucket_cursor = bucket_base + 260;          // 256
    int2* colval       = (int2*)(bucket_cursor + 256 + 4);  // E, 8B-aligned
    __half* Tall       = (__half*)(colval + E);             // K * N*FDIM fp16
    __half* WT         = Tall + (size_t)K * N * FDIM;       // K*64*64 fp16
    // binned arrays alias T0/T1 (dead before convert/pass1 write them)
    int2* binned_sv    = (int2*)Tall;                       // E * 8B
    unsigned short* binned_d = (unsigned short*)(Tall + (size_t)N * FDIM);  // E * 2B

    hipMemsetAsync(bucket_cnt, 0, 256 * sizeof(int), stream);

    bucket_hist_kernel<<<512, 256, 0, stream>>>(dst, bucket_cnt, E);
    bucket_scan_kernel<<<1, 256, 0, stream>>>(bucket_cnt, bucket_base, bucket_cursor);

    int bb = (E + CH - 1) / CH;
    bin_kernel<<<bb, 256, 0, stream>>>(src, dst, w, bucket_cursor,
                                       binned_sv, binned_d, E, NB);
    csr_kernel<<<NB, 1024, 0, stream>>>(bucket_base, binned_sv, binned_d,
                                        row_start, counts, colval, N);

    // T0' = x (fp16); W'T prep (sigma folded into W, fp16)
    convert_kernel<<<(N * FDIM + 1023) / 1024, 256, 0, stream>>>(x, Tall, N * FDIM);
    prep_wt_kernel<<<(K * FDIM * FDIM + 255) / 256, 256, 0, stream>>>(weight, WT, K);

    size_t NT = (size_t)N * FDIM;
    __half* T[8];
    for (int k = 0; k < K && k < 8; ++k) T[k] = Tall + (size_t)k * NT;

    int pb = (N + 3) / 4;
    pass1_kernel<<<pb, 256, 0, stream>>>(T[0], row_start, counts, colval, T[1], N);
    for (int k = 2; k < K; ++k) {
        passk_kernel<<<pb, 256, 0, stream>>>(T[k-1], T[k-2], T[k], row_start, counts,
                                             colval, N);
    }

    int tiles = (N + 15) >> 4;
    final_mfma_kernel<<<(tiles + 3) / 4, 256, 0, stream>>>(Tall, WT, bias, out, N, K);
}

// Round 12
// 799.338 us; speedup vs baseline: 1.0211x; 1.0211x over previous
//
#include <hip/hip_runtime.h>
#include <hip/hip_fp16.h>

#define FDIM 64
#define NB_SHIFT 10                  // 1024 nodes per bucket
#define NB_PAD 256                   // padded scan width (NB <= 256)
#define CH 4096                      // edges per bin-chunk

typedef __attribute__((ext_vector_type(8))) _Float16 half8;
typedef __attribute__((ext_vector_type(4))) float floatx4;

// ---------------- bucket-level CSR build (no per-node global atomics) ----------------

// 196-bucket histogram: LDS-local, one global atomicAdd per bucket per block.
__global__ __launch_bounds__(256) void bucket_hist_kernel(
        const int* __restrict__ dst, int* __restrict__ bucket_cnt, int E) {
    __shared__ int h[NB_PAD];
    for (int i = threadIdx.x; i < NB_PAD; i += 256) h[i] = 0;
    __syncthreads();
    int stride = gridDim.x * 256;
    for (int e = blockIdx.x * 256 + threadIdx.x; e < E; e += stride)
        atomicAdd(&h[dst[e] >> NB_SHIFT], 1);
    __syncthreads();
    for (int i = threadIdx.x; i < NB_PAD; i += 256)
        if (h[i]) atomicAdd(&bucket_cnt[i], h[i]);
}

// single block: exclusive scan of bucket counts -> bucket_base[0..NB] and cursors.
__global__ __launch_bounds__(256) void bucket_scan_kernel(
        const int* __restrict__ bucket_cnt, int* __restrict__ bucket_base,
        int* __restrict__ bucket_cursor) {
    __shared__ int s[NB_PAD];
    int t = threadIdx.x;
    int v = bucket_cnt[t];
    s[t] = v;
    __syncthreads();
    for (int off = 1; off < 256; off <<= 1) {
        int x = (t >= off) ? s[t - off] : 0;
        __syncthreads();
        s[t] += x;
        __syncthreads();
    }
    int excl = s[t] - v;
    bucket_base[t] = excl;                  // for t >= NB this equals E (cnt=0)
    if (t == 255) bucket_base[256] = s[255];
    bucket_cursor[t] = excl;
}

// Stage 1: bin edges by dst bucket with LDS staging + chunked coalesced flush.
__global__ __launch_bounds__(256) void bin_kernel(
        const int* __restrict__ src, const int* __restrict__ dst,
        const float* __restrict__ w, int* __restrict__ bucket_cursor,
        int2* __restrict__ binned_sv, unsigned short* __restrict__ binned_d,
        int E, int NB) {
    __shared__ int2 stage_sv[CH];           // 32 KB
    __shared__ int  stage_d[CH];            // 16 KB
    __shared__ int hist[NB_PAD], offs0[NB_PAD], run[NB_PAD], base[NB_PAD];

    int t = threadIdx.x;
    int c0 = blockIdx.x * CH;
    int valid = E - c0; if (valid > CH) valid = CH;

    for (int b = t; b < NB_PAD; b += 256) hist[b] = 0;
    __syncthreads();

    int  myd[16];
    int2 mysv[16];
    #pragma unroll
    for (int j = 0; j < 16; ++j) {
        int i = t + j * 256;
        if (i < valid) {
            int e = c0 + i;
            int d = dst[e];
            myd[j] = d;
            mysv[j] = make_int2(src[e], __float_as_int(-w[e]));  // norm = -w
            atomicAdd(&hist[d >> NB_SHIFT], 1);
        } else myd[j] = -1;
    }
    __syncthreads();

    // inclusive scan of hist (256-wide Hillis-Steele) -> exclusive offs
    offs0[t] = hist[t];
    __syncthreads();
    for (int off = 1; off < 256; off <<= 1) {
        int x = (t >= off) ? offs0[t - off] : 0;
        __syncthreads();
        offs0[t] += x;
        __syncthreads();
    }
    int cnt_b = hist[t];
    int excl = offs0[t] - cnt_b;
    __syncthreads();
    offs0[t] = excl;
    run[t] = excl;
    base[t] = (t < NB && cnt_b > 0) ? atomicAdd(&bucket_cursor[t], cnt_b) : 0;
    __syncthreads();

    // scatter into LDS grouped by bucket
    #pragma unroll
    for (int j = 0; j < 16; ++j) {
        if (myd[j] >= 0) {
            int b = myd[j] >> NB_SHIFT;
            int pos = atomicAdd(&run[b], 1);
            stage_sv[pos] = mysv[j];
            stage_d[pos]  = myd[j];
        }
    }
    __syncthreads();

    // flush: consecutive LDS entries of a bucket -> consecutive global slots
    for (int i = t; i < valid; i += 256) {
        int d = stage_d[i];
        int b = d >> NB_SHIFT;
        int g = base[b] + (i - offs0[b]);
        binned_sv[g] = stage_sv[i];
        binned_d[g]  = (unsigned short)(d & ((1 << NB_SHIFT) - 1));
    }
}

// Stage 2: one 1024-thread block per bucket. Local histogram + local scan in LDS
// produce row_start/counts for the bucket's nodes (no global atomics), then edges
// are placed; the ~130KB CSR window stays in ONE XCD's L2.
__global__ __launch_bounds__(1024) void csr_kernel(
        const int* __restrict__ bucket_base, const int2* __restrict__ binned_sv,
        const unsigned short* __restrict__ binned_d,
        int* __restrict__ row_start, int* __restrict__ counts,
        int2* __restrict__ colval, int N) {
    __shared__ int lhist[1 << NB_SHIFT];    // 4 KB
    __shared__ int lscan[1 << NB_SHIFT];    // 4 KB
    int b = blockIdx.x;
    int t = threadIdx.x;
    int nbase = b << NB_SHIFT;
    int lo = bucket_base[b];
    int hi = bucket_base[b + 1];

    lhist[t] = 0;
    __syncthreads();
    for (int i = lo + t; i < hi; i += 1024)
        atomicAdd(&lhist[binned_d[i]], 1);
    __syncthreads();

    int v = lhist[t];
    lscan[t] = v;
    __syncthreads();
    for (int off = 1; off < 1024; off <<= 1) {
        int x = (t >= off) ? lscan[t - off] : 0;
        __syncthreads();
        lscan[t] += x;
        __syncthreads();
    }
    int rs = lo + lscan[t] - v;             // node's CSR start
    int node = nbase + t;
    if (node < N) {
        row_start[node] = rs;
        counts[node] = v;
    }
    __syncthreads();
    lscan[t] = rs;                          // reuse as local cursor
    __syncthreads();

    for (int i = lo + t; i < hi; i += 1024) {
        int2 sv = binned_sv[i];
        int p = atomicAdd(&lscan[binned_d[i]], 1);
        colval[p] = sv;
    }
}

// ---------------- convert x -> fp16 (T0') ----------------

__global__ void convert_kernel(const float* __restrict__ x, __half* __restrict__ XH,
                               int total) {
    int i = (blockIdx.x * blockDim.x + threadIdx.x) * 4;
    if (i < total) {
        float4 v = *(const float4*)(x + i);
        __half2 h0 = __floats2half2_rn(v.x, v.y);
        __half2 h1 = __floats2half2_rn(v.z, v.w);
        int2 packed = make_int2(*(int*)&h0, *(int*)&h1);
        *(int2*)((char*)XH + (size_t)i * 2) = packed;
    }
}

// ---------------- prep W'T: WT[o][tk*64+fin] = 4^tk * W[tk][fin][o], fp16 ----------------

__global__ void prep_wt_kernel(const float* __restrict__ W, __half* __restrict__ WT,
                               int K) {
    int i = blockIdx.x * blockDim.x + threadIdx.x;     // over K*64*64
    if (i < K * FDIM * FDIM) {
        int tk  = i / (FDIM * FDIM);
        int rem = i - tk * FDIM * FDIM;
        int fin = rem >> 6;
        int o   = rem & 63;
        float sig = (float)(1 << (2 * tk));            // 4^tk
        WT[(size_t)o * (K * FDIM) + tk * FDIM + fin] = __float2half(sig * W[i]);
    }
}

// ---------------- Chebyshev passes ----------------
// Wave per node, lane = feature. Stored T's are fp16, scaled by sigma_k = 4^k.
// Edge list (<=64 edges) loaded with ONE per-lane int2 load, broadcast via __shfl.
// 16/8/4-deep gather batching for outstanding-miss depth.
// NOTE (R11 post-mortem): nontemporal hints on the streams REGRESSED (+5us/pass,
// FETCH unchanged) -- gather traffic is compulsory; keep plain loads/stores.

#define GATHER_LOOP(SRC, ACC)                                                       \
    {                                                                               \
        int m = (cnt < 64) ? cnt : 64;                                              \
        int2 my = (lane < m) ? cv[lane] : make_int2(0, 0);                          \
        int cx = my.x;                                                              \
        float vv = __int_as_float(my.y);                                            \
        int j = 0;                                                                  \
        for (; j + 16 <= m; j += 16) {                                              \
            int c0 = __shfl(cx, j+0);  float v0 = __shfl(vv, j+0);                  \
            int c1 = __shfl(cx, j+1);  float v1 = __shfl(vv, j+1);                  \
            int c2 = __shfl(cx, j+2);  float v2 = __shfl(vv, j+2);                  \
            int c3 = __shfl(cx, j+3);  float v3 = __shfl(vv, j+3);                  \
            int c4 = __shfl(cx, j+4);  float v4 = __shfl(vv, j+4);                  \
            int c5 = __shfl(cx, j+5);  float v5 = __shfl(vv, j+5);                  \
            int c6 = __shfl(cx, j+6);  float v6 = __shfl(vv, j+6);                  \
            int c7 = __shfl(cx, j+7);  float v7 = __shfl(vv, j+7);                  \
            int c8 = __shfl(cx, j+8);  float v8 = __shfl(vv, j+8);                  \
            int c9 = __shfl(cx, j+9);  float v9 = __shfl(vv, j+9);                  \
            int ca = __shfl(cx, j+10); float va = __shfl(vv, j+10);                 \
            int cb = __shfl(cx, j+11); float vb = __shfl(vv, j+11);                 \
            int cc = __shfl(cx, j+12); float vc = __shfl(vv, j+12);                 \
            int cd = __shfl(cx, j+13); float vd = __shfl(vv, j+13);                 \
            int ce = __shfl(cx, j+14); float ve = __shfl(vv, j+14);                 \
            int cf = __shfl(cx, j+15); float vf = __shfl(vv, j+15);                 \
            float t0 = __half2float(SRC[(size_t)c0 * FDIM + lane]);                 \
            float t1 = __half2float(SRC[(size_t)c1 * FDIM + lane]);                 \
            float t2 = __half2float(SRC[(size_t)c2 * FDIM + lane]);                 \
            float t3 = __half2float(SRC[(size_t)c3 * FDIM + lane]);                 \
            float t4 = __half2float(SRC[(size_t)c4 * FDIM + lane]);                 \
            float t5 = __half2float(SRC[(size_t)c5 * FDIM + lane]);                 \
            float t6 = __half2float(SRC[(size_t)c6 * FDIM + lane]);                 \
            float t7 = __half2float(SRC[(size_t)c7 * FDIM + lane]);                 \
            float t8 = __half2float(SRC[(size_t)c8 * FDIM + lane]);                 \
            float t9 = __half2float(SRC[(size_t)c9 * FDIM + lane]);                 \
            float ta = __half2float(SRC[(size_t)ca * FDIM + lane]);                 \
            float tb = __half2float(SRC[(size_t)cb * FDIM + lane]);                 \
            float tc = __half2float(SRC[(size_t)cc * FDIM + lane]);                 \
            float td = __half2float(SRC[(size_t)cd * FDIM + lane]);                 \
            float te = __half2float(SRC[(size_t)ce * FDIM + lane]);                 \
            float tf = __half2float(SRC[(size_t)cf * FDIM + lane]);                 \
            ACC += v0*t0 + v1*t1 + v2*t2 + v3*t3 + v4*t4 + v5*t5 + v6*t6 + v7*t7;   \
            ACC += v8*t8 + v9*t9 + va*ta + vb*tb + vc*tc + vd*td + ve*te + vf*tf;   \
        }                                                                           \
        for (; j + 4 <= m; j += 4) {                                                \
            int c0 = __shfl(cx, j+0); float v0 = __shfl(vv, j+0);                   \
            int c1 = __shfl(cx, j+1); float v1 = __shfl(vv, j+1);                   \
            int c2 = __shfl(cx, j+2); float v2 = __shfl(vv, j+2);                   \
            int c3 = __shfl(cx, j+3); float v3 = __shfl(vv, j+3);                   \
            float t0 = __half2float(SRC[(size_t)c0 * FDIM + lane]);                 \
            float t1 = __half2float(SRC[(size_t)c1 * FDIM + lane]);                 \
            float t2 = __half2float(SRC[(size_t)c2 * FDIM + lane]);                 \
            float t3 = __half2float(SRC[(size_t)c3 * FDIM + lane]);                 \
            ACC += v0*t0 + v1*t1 + v2*t2 + v3*t3;                                   \
        }                                                                           \
        for (; j < m; ++j) {                                                        \
            int c = __shfl(cx, j); float v = __shfl(vv, j);                         \
            ACC += v * __half2float(SRC[(size_t)c * FDIM + lane]);                  \
        }                                                                           \
        for (int e2 = 64; e2 < cnt; ++e2) {  /* astronomically rare */              \
            int2 a = cv[e2];                                                        \
            ACC += __int_as_float(a.y) * __half2float(SRC[(size_t)a.x * FDIM + lane]); \
        }                                                                           \
    }

__global__ __launch_bounds__(256, 8) void pass1_kernel(
        const __half* __restrict__ XH, const int* __restrict__ row_start,
        const int* __restrict__ counts, const int2* __restrict__ colval,
        __half* __restrict__ T1H, int N) {
    int wid = threadIdx.x >> 6;
    int lane = threadIdx.x & 63;
    int node = blockIdx.x * 4 + wid;
    if (node >= N) return;

    float acc = -__half2float(XH[(size_t)node * FDIM + lane]);   // self loop (norm -1)
    int s = row_start[node];
    int cnt = counts[node];
    const int2* cv = colval + s;
    GATHER_LOOP(XH, acc)
    T1H[(size_t)node * FDIM + lane] = __float2half(acc * 0.25f);  // sigma1 = 4
}

// T'_next = 0.5*prop'(T'_cur) - T'_prev/16
__global__ __launch_bounds__(256, 8) void passk_kernel(
        const __half* __restrict__ TcH, const __half* __restrict__ TpH,
        __half* __restrict__ TnH, const int* __restrict__ row_start,
        const int* __restrict__ counts, const int2* __restrict__ colval, int N) {
    int wid = threadIdx.x >> 6;
    int lane = threadIdx.x & 63;
    int node = blockIdx.x * 4 + wid;
    if (node >= N) return;

    size_t self = (size_t)node * FDIM + lane;
    int s = row_start[node];
    int cnt = counts[node];
    const int2* cv = colval + s;
    float acc = -__half2float(TcH[self]);                        // self loop
    GATHER_LOOP(TcH, acc)
    float tns = 0.5f * acc - 0.0625f * __half2float(TpH[self]);
    TnH[self] = __float2half(tns);
}

// ---------------- final: out = [T'0|...|T'5] @ W'T^T + bias via MFMA ----------------

__global__ __launch_bounds__(256) void final_mfma_kernel(
        const __half* __restrict__ Tall, const __half* __restrict__ WT,
        const float* __restrict__ bias, float* __restrict__ out,
        int N, int K) {
    int wid = threadIdx.x >> 6;
    int lane = threadIdx.x & 63;
    int tile = blockIdx.x * 4 + wid;       // 16 nodes per wave-tile
    int nodeBase = tile << 4;
    if (nodeBase >= N) return;
    size_t NT = (size_t)N * FDIM;
    int Kflat = K * FDIM;                  // 384

    int m = lane & 15;
    int kgrp = lane >> 4;                  // 0..3
    int nodeA = nodeBase + m;              // A-fragment row
    bool aok = nodeA < N;

    floatx4 acc[4];
    #pragma unroll
    for (int f = 0; f < 4; ++f) {
        float bv = bias[f * 16 + m];
        acc[f] = (floatx4){bv, bv, bv, bv};
    }

    for (int kc = 0; kc < Kflat / 32; ++kc) {
        int tk = kc >> 1;
        int feat = ((kc & 1) << 5) + (kgrp << 3);    // 0..56, 8-aligned
        half8 a = aok ? *(const half8*)(Tall + (size_t)tk * NT + (size_t)nodeA * FDIM + feat)
                      : (half8)(_Float16)0;
        int kOff = (kc << 5) + (kgrp << 3);
        #pragma unroll
        for (int f = 0; f < 4; ++f) {
            half8 b = *(const half8*)(WT + (size_t)(f * 16 + m) * Kflat + kOff);
            acc[f] = __builtin_amdgcn_mfma_f32_16x16x32_f16(a, b, acc[f], 0, 0, 0);
        }
    }

    #pragma unroll
    for (int f = 0; f < 4; ++f) {
        #pragma unroll
        for (int r = 0; r < 4; ++r) {
            int nrow = nodeBase + (kgrp << 2) + r;
            if (nrow < N) out[(size_t)nrow * FDIM + f * 16 + m] = acc[f][r];
        }
    }
}

// ---------------- host ----------------

extern "C" void kernel_launch(void* const* d_in, const int* in_sizes, int n_in,
                              void* d_out, int out_size, void* d_ws, size_t ws_size,
                              hipStream_t stream) {
    const float* x      = (const float*)d_in[0];
    const int*   idx    = (const int*)d_in[1];
    const float* w      = (const float*)d_in[2];
    const float* weight = (const float*)d_in[3];
    const float* bias   = (const float*)d_in[4];
    float* out = (float*)d_out;

    const int N = in_sizes[0] / FDIM;
    const int E = in_sizes[2];
    const int K = in_sizes[3] / (FDIM * FDIM);
    const int NB = (N + (1 << NB_SHIFT) - 1) >> NB_SHIFT;

    const int* src = idx;
    const int* dst = idx + E;

    int* counts        = (int*)d_ws;                 // N
    int* row_start     = counts + N;                 // N
    int* bucket_cnt    = row_start + N;              // 256
    int* bucket_base   = bucket_cnt + 256;           // 260
    int* bucket_cursor = bucket_base + 260;          // 256
    int2* colval       = (int2*)(bucket_cursor + 256 + 4);  // E, 8B-aligned
    __half* Tall       = (__half*)(colval + E);             // K * N*FDIM fp16
    __half* WT         = Tall + (size_t)K * N * FDIM;       // K*64*64 fp16
    // binned arrays alias T0/T1 (dead before convert/pass1 write them)
    int2* binned_sv    = (int2*)Tall;                       // E * 8B
    unsigned short* binned_d = (unsigned short*)(Tall + (size_t)N * FDIM);  // E * 2B

    hipMemsetAsync(bucket_cnt, 0, 256 * sizeof(int), stream);

    bucket_hist_kernel<<<512, 256, 0, stream>>>(dst, bucket_cnt, E);
    bucket_scan_kernel<<<1, 256, 0, stream>>>(bucket_cnt, bucket_base, bucket_cursor);

    int bb = (E + CH - 1) / CH;
    bin_kernel<<<bb, 256, 0, stream>>>(src, dst, w, bucket_cursor,
                                       binned_sv, binned_d, E, NB);
    csr_kernel<<<NB, 1024, 0, stream>>>(bucket_base, binned_sv, binned_d,
                                        row_start, counts, colval, N);

    // T0' = x (fp16); W'T prep (sigma folded into W, fp16)
    convert_kernel<<<(N * FDIM + 1023) / 1024, 256, 0, stream>>>(x, Tall, N * FDIM);
    prep_wt_kernel<<<(K * FDIM * FDIM + 255) / 256, 256, 0, stream>>>(weight, WT, K);

    size_t NT = (size_t)N * FDIM;
    __half* T[8];
    for (int k = 0; k < K && k < 8; ++k) T[k] = Tall + (size_t)k * NT;

    int pb = (N + 3) / 4;
    pass1_kernel<<<pb, 256, 0, stream>>>(T[0], row_start, counts, colval, T[1], N);
    for (int k = 2; k < K; ++k) {
        passk_kernel<<<pb, 256, 0, stream>>>(T[k-1], T[k-2], T[k], row_start, counts,
                                             colval, N);
    }

    int tiles = (N + 15) >> 4;
    final_mfma_kernel<<<(tiles + 3) / 4, 256, 0, stream>>>(Tall, WT, bias, out, N, K);
}